// Round 4
// baseline (206.041 us; speedup 1.0000x reference)
//
#include <hip/hip_runtime.h>
#include <math.h>

#define B_ 2
#define L_ 1024
#define D_ 512
#define NROW (B_*L_)            // 2048
#define RS 896                  // R stride: key16|query16|g1 256|v 512|pad 96
#define PI_F 3.14159274f
#define TWO_PI_F 6.28318548f

typedef __attribute__((ext_vector_type(8))) short bf16x8;
typedef __attribute__((ext_vector_type(4))) float f32x4;

__device__ __forceinline__ unsigned short f2bf(float f) {
    unsigned u = __float_as_uint(f);
    unsigned r = (u + 0x7FFFu + ((u >> 16) & 1u)) >> 16;
    return (unsigned short)r;
}

// ---------------- weight prep: tiled transpose + bf16 cast ----------------
// W[1408][512] bf16, n-major: rows 0-15 key, 16-31 query, 32-287 g1,
// 288-799 v, 800-895 zero, 896-1407 out_w^T
__global__ __launch_bounds__(256) void k_prep_w(
    const float* __restrict__ keyw, const float* __restrict__ qryw,
    const float* __restrict__ g1w, const float* __restrict__ vw,
    const float* __restrict__ outw, unsigned short* __restrict__ W)
{
    const int nt = blockIdx.x % 22;
    const int kt = blockIdx.x / 22;     // 0..7
    const int n0 = nt * 64, k0 = kt * 64;
    __shared__ unsigned short tile[64 * 68];   // [k][n], stride 68
    const int tn = threadIdx.x & 63;
    const int tk4 = threadIdx.x >> 6;   // 0..3
    const int n = n0 + tn;
    const float* src = nullptr; int stride = 0, col = 0;
    if (n < 16)        { src = keyw; stride = 16;  col = n; }
    else if (n < 32)   { src = qryw; stride = 16;  col = n - 16; }
    else if (n < 288)  { src = g1w;  stride = 256; col = n - 32; }
    else if (n < 800)  { src = vw;   stride = 512; col = n - 288; }
    else if (n < 896)  { src = nullptr; }
    else               { src = outw; stride = 512; col = n - 896; }
    #pragma unroll
    for (int r = 0; r < 16; ++r) {
        int k = k0 + tk4 * 16 + r;
        float v = src ? src[(size_t)k * stride + col] : 0.f;
        tile[(tk4 * 16 + r) * 68 + tn] = f2bf(v);
    }
    __syncthreads();
    #pragma unroll
    for (int r = 0; r < 16; ++r) {
        int nn = n0 + tk4 * 16 + r;
        W[(size_t)nn * 512 + k0 + tn] = tile[tn * 68 + tk4 * 16 + r];
    }
}

// ---------------- GEMM1 (MFMA): R[2048][896] = x @ W[0:896]^T, fp32-A inline cast ----------------
__global__ __launch_bounds__(256) void k_gemm1(
    const float* __restrict__ x,             // [2048][512] fp32
    const unsigned short* __restrict__ Bt,   // [896][512] bf16 (n-major)
    const float* __restrict__ g1b, const float* __restrict__ vb,
    float* __restrict__ C)
{
    __shared__ unsigned short As[64 * 32];
    __shared__ unsigned short Bs[128 * 32];
    const int tid = threadIdx.x;
    const int w = tid >> 6;
    const int lane = tid & 63;
    const int m0 = blockIdx.y * 64;
    const int n0 = blockIdx.x * 128;
    const int srow = tid >> 2;          // 0..63
    const int scol = (tid & 3) * 8;     // 0,8,16,24

    f32x4 acc[4][2];
    #pragma unroll
    for (int mt = 0; mt < 4; ++mt)
        #pragma unroll
        for (int nt = 0; nt < 2; ++nt)
            acc[mt][nt] = (f32x4){0.f, 0.f, 0.f, 0.f};

    const float* ap = x + (size_t)(m0 + srow) * 512 + scol;
    const unsigned short* bp0 = Bt + (size_t)(n0 + srow) * 512 + scol;
    const unsigned short* bp1 = Bt + (size_t)(n0 + 64 + srow) * 512 + scol;
    const int quad = lane >> 4, r16 = lane & 15;

    for (int k0 = 0; k0 < 512; k0 += 32) {
        float4 a0 = *(const float4*)(ap + k0);
        float4 a1 = *(const float4*)(ap + k0 + 4);
        int4 bv0 = *(const int4*)(bp0 + k0);
        int4 bv1 = *(const int4*)(bp1 + k0);
        int4 av;
        av.x = (int)f2bf(a0.x) | ((int)f2bf(a0.y) << 16);
        av.y = (int)f2bf(a0.z) | ((int)f2bf(a0.w) << 16);
        av.z = (int)f2bf(a1.x) | ((int)f2bf(a1.y) << 16);
        av.w = (int)f2bf(a1.z) | ((int)f2bf(a1.w) << 16);
        __syncthreads();
        *(int4*)&As[srow * 32 + scol] = av;
        *(int4*)&Bs[srow * 32 + scol] = bv0;
        *(int4*)&Bs[(64 + srow) * 32 + scol] = bv1;
        __syncthreads();
        bf16x8 af[4], bfr[2];
        #pragma unroll
        for (int mt = 0; mt < 4; ++mt)
            af[mt] = *(const bf16x8*)&As[(mt * 16 + r16) * 32 + quad * 8];
        #pragma unroll
        for (int nt = 0; nt < 2; ++nt)
            bfr[nt] = *(const bf16x8*)&Bs[(w * 32 + nt * 16 + r16) * 32 + quad * 8];
        #pragma unroll
        for (int mt = 0; mt < 4; ++mt)
            #pragma unroll
            for (int nt = 0; nt < 2; ++nt)
                acc[mt][nt] = __builtin_amdgcn_mfma_f32_16x16x32_bf16(
                    af[mt], bfr[nt], acc[mt][nt], 0, 0, 0);
    }

    #pragma unroll
    for (int mt = 0; mt < 4; ++mt) {
        #pragma unroll
        for (int nt = 0; nt < 2; ++nt) {
            const int n = n0 + w * 32 + nt * 16 + r16;
            float bias = 0.f;
            if (n >= 288 && n < 800) bias = vb[n - 288];
            else if (n >= 32 && n < 288) bias = g1b[n - 32];
            #pragma unroll
            for (int i = 0; i < 4; ++i) {
                const int m = m0 + mt * 16 + quad * 4 + i;
                C[(size_t)m * RS + n] = acc[mt][nt][i] + bias;
            }
        }
    }
}

// ---------------- phasors, jk/jq, pos phasors, gate (4 rows/block, wave=row) ----------------
__global__ __launch_bounds__(256) void k_phasor(
    const float* __restrict__ R, const float* __restrict__ pf,
    const float* __restrict__ g2w, const float* __restrict__ g2b,
    float* __restrict__ scal)
{
    const int row = blockIdx.x * 4 + (threadIdx.x >> 6);
    const int lane = threadIdx.x & 63;
    const int l = row & (L_ - 1);
    float* sc = scal + (size_t)row * 128;
    const float* r = R + (size_t)row * RS;

    float part = 0.f;
    #pragma unroll
    for (int j = 0; j < 4; ++j) {
        float v = r[32 + lane * 4 + j];
        float h = 0.5f * v * (1.0f + erff(v * 0.70710678f));
        part += h * g2w[lane * 4 + j];
    }
    #pragma unroll
    for (int off = 32; off > 0; off >>= 1) part += __shfl_down(part, off, 64);
    if (lane == 0) sc[112] = 1.0f / (1.0f + expf(-(part + g2b[0])));

    float pr = 1.f, pim = 0.f;
    if (lane < 32) {
        float a = tanhf(r[lane]) * PI_F;
        float sv, cv;
        sincosf(a, &sv, &cv);
        int t = lane & 15;
        if (lane < 16) { sc[t] = cv; sc[16 + t] = sv; }
        else           { sc[32 + t] = cv; sc[48 + t] = sv; }
        pr = cv; pim = sv;
    }
    #pragma unroll
    for (int m = 4; m <= 8; m <<= 1) {
        float orr = __shfl_xor(pr, m, 64);
        float oii = __shfl_xor(pim, m, 64);
        float nr = pr * orr - pim * oii;
        float ni = pr * oii + pim * orr;
        pr = nr; pim = ni;
    }
    if (lane < 4)                     { sc[64 + lane] = pr; sc[68 + lane] = pim; }
    else if (lane >= 16 && lane < 20) { sc[72 + lane - 16] = pr; sc[76 + lane - 16] = pim; }

    if (lane >= 32 && lane < 48) {
        int p = lane - 32;
        float theta = ((float)l * pf[p]) * TWO_PI_F;
        float sv, cv;
        sincosf(theta, &sv, &cv);
        sc[80 + p] = cv;
        sc[96 + p] = sv;
    }
}

// ---------------- wg: block scan of jk over L, surprise gate ----------------
__global__ __launch_bounds__(1024) void k_wg(
    float* __restrict__ scal,
    const float* __restrict__ res_scale, const float* __restrict__ res_thr,
    const float* __restrict__ sur_scale, const float* __restrict__ sur_bias)
{
    const int b = blockIdx.x;
    const int l = threadIdx.x;
    const size_t row = (size_t)(b * L_ + l) * 128;
    float v[8], own[8];
    #pragma unroll
    for (int c2 = 0; c2 < 8; ++c2) { v[c2] = scal[row + 64 + c2]; own[c2] = v[c2]; }
    const int lane = l & 63;
    const int wave = l >> 6;
    #pragma unroll
    for (int off = 1; off < 64; off <<= 1) {
        float o[8];
        #pragma unroll
        for (int c2 = 0; c2 < 8; ++c2) o[c2] = __shfl_up(v[c2], off, 64);
        if (lane >= off) {
            #pragma unroll
            for (int c2 = 0; c2 < 8; ++c2) v[c2] += o[c2];
        }
    }
    __shared__ float wtot[16][8];
    if (lane == 63) {
        #pragma unroll
        for (int c2 = 0; c2 < 8; ++c2) wtot[wave][c2] = v[c2];
    }
    __syncthreads();
    float pre[8] = {0,0,0,0,0,0,0,0};
    for (int w2 = 0; w2 < wave; ++w2) {
        #pragma unroll
        for (int c2 = 0; c2 < 8; ++c2) pre[c2] += wtot[w2][c2];
    }
    float km[8];
    #pragma unroll
    for (int c2 = 0; c2 < 8; ++c2) km[c2] = pre[c2] + v[c2] - own[c2];
    float mag = 0.f;
    #pragma unroll
    for (int pp = 0; pp < 4; ++pp) {
        float jqr = scal[row + 72 + pp], jqi = scal[row + 76 + pp];
        float re = km[pp] * jqr + km[4 + pp] * jqi;
        float im = km[4 + pp] * jqr - km[pp] * jqi;
        mag += sqrtf(re * re + im * im);
    }
    mag *= 0.25f;
    float posn = fmaxf((float)l, 1.0f);
    float nres = mag / sqrtf(posn);
    float scl = fminf(fmaxf(res_scale[0], 1.0f), 20.0f);
    float thr = fminf(fmaxf(res_thr[0], 0.1f), 0.9f);
    float sur = 0.5f * (1.0f - tanhf(scl * (nres - thr)));
    float wgv = 1.0f / (1.0f + expf(-(sur_scale[0] * (sur - 0.5f) + sur_bias[0])));
    scal[row + 113] = wgv;
}

// ---------------- pass A: chunked scans, local contributions + chunk totals ----------------
template<int CCH, int CLEN>
__global__ __launch_bounds__(256) void k_passA(
    const float* __restrict__ scal, const float* __restrict__ R,
    const float* __restrict__ setw, const float* __restrict__ posw,
    float* __restrict__ loc, float* __restrict__ T)
{
    const int bx = blockIdx.x;           // B*CCH*2
    const int b = bx / (CCH * 2);
    const int rem = bx % (CCH * 2);
    const int c = rem >> 1;
    const int half = rem & 1;
    const int d = half * 256 + threadIdx.x;

    float s0 = setw[0], s1 = setw[1], s2 = setw[2], s3 = setw[3];
    float mx = fmaxf(fmaxf(s0, s1), fmaxf(s2, s3));
    float e0 = expf(s0 - mx), e1 = expf(s1 - mx), e2 = expf(s2 - mx), e3 = expf(s3 - mx);
    float esum = e0 + e1 + e2 + e3;
    float w[4] = {e0 / esum, e1 / esum, e2 / esum, e3 / esum};
    float sw = 1.0f / (1.0f + expf(-posw[0]));

    float Sr[16] = {}, Si[16] = {}, Xr[4] = {}, Xi[4] = {}, Pr[16] = {}, Pi[16] = {};

    for (int i = 0; i < CLEN; ++i) {
        const int l = c * CLEN + i;
        const size_t row = (size_t)(b * L_ + l);
        const float4* sc4 = (const float4*)(scal + row * 128);
        float V = R[row * RS + 288 + d];
        float4 gw = sc4[28];
        float gate = gw.x, wg = gw.y;
        float Vg = V * wg;
        float pb = 0.f, cross = 0.f, pos = 0.f;
        #pragma unroll
        for (int g4 = 0; g4 < 4; ++g4) {
            float kr[4], ki[4], qr[4], qi[4];
            *(float4*)kr = sc4[g4];      *(float4*)ki = sc4[4 + g4];
            *(float4*)qr = sc4[8 + g4];  *(float4*)qi = sc4[12 + g4];
            #pragma unroll
            for (int j = 0; j < 4; ++j) {
                int t = 4 * g4 + j;
                Sr[t] += kr[j] * Vg; Si[t] += ki[j] * Vg;
                pb += w[g4] * (Sr[t] * qr[j] + Si[t] * qi[j]);
            }
        }
        {
            float jkr[4], jki[4], jqr[4], jqi[4];
            *(float4*)jkr = sc4[16]; *(float4*)jki = sc4[17];
            *(float4*)jqr = sc4[18]; *(float4*)jqi = sc4[19];
            #pragma unroll
            for (int pp = 0; pp < 4; ++pp) {
                Xr[pp] += jkr[pp] * Vg; Xi[pp] += jki[pp] * Vg;
                cross += Xr[pp] * jqr[pp] + Xi[pp] * jqi[pp];
            }
        }
        #pragma unroll
        for (int g4 = 0; g4 < 4; ++g4) {
            float phr[4], phi[4];
            *(float4*)phr = sc4[20 + g4]; *(float4*)phi = sc4[24 + g4];
            #pragma unroll
            for (int j = 0; j < 4; ++j) {
                int p = 4 * g4 + j;
                Pr[p] += phr[j] * V; Pi[p] += phi[j] * V;
                pos += Pr[p] * phr[j] + Pi[p] * phi[j];
            }
        }
        float comb = gate * ((pb + cross) * 0.2f) + (1.0f - gate) * (sw * pos);
        loc[row * D_ + d] = comb;
    }
    const size_t tb = ((size_t)(b * CCH + c) * 72) * D_ + d;
    #pragma unroll
    for (int t = 0; t < 16; ++t) { T[tb + (size_t)(2*t)*D_] = Sr[t]; T[tb + (size_t)(2*t+1)*D_] = Si[t]; }
    #pragma unroll
    for (int pp = 0; pp < 4; ++pp) { T[tb + (size_t)(32+2*pp)*D_] = Xr[pp]; T[tb + (size_t)(33+2*pp)*D_] = Xi[pp]; }
    #pragma unroll
    for (int p = 0; p < 16; ++p) { T[tb + (size_t)(40+2*p)*D_] = Pr[p]; T[tb + (size_t)(41+2*p)*D_] = Pi[p]; }
}

// ---------------- in-place exclusive scan over chunk totals (8-wide ILP batches) ----------------
template<int CCH>
__global__ __launch_bounds__(256) void k_scan(float* __restrict__ T)
{
    const int idx = blockIdx.x * 256 + threadIdx.x;     // < 2*72*512 = 73728
    const int d = idx & 511;
    const int ch = (idx >> 9) % 72;
    const int b = idx / (512 * 72);
    const size_t base = ((size_t)b * CCH * 72 + ch) * D_ + d;
    const size_t cstride = (size_t)72 * D_;
    float run = 0.f;
    for (int c0 = 0; c0 < CCH; c0 += 8) {
        float v[8];
        #pragma unroll
        for (int j = 0; j < 8; ++j) v[j] = T[base + (size_t)(c0 + j) * cstride];
        #pragma unroll
        for (int j = 0; j < 8; ++j) {
            T[base + (size_t)(c0 + j) * cstride] = run;
            run += v[j];
        }
    }
}

// ---------------- pass B fused with output GEMM ----------------
// 16 rows/block: prefix-combine + /norm + LayerNorm -> yn (bf16, LDS) ->
// out = x + yn @ out_w^T + out_b  via MFMA (M=16, wave owns 64 n-cols)
template<int CCH, int CLEN>
__global__ __launch_bounds__(512) void k_passB_out(
    const float* __restrict__ scal, const float* __restrict__ T,
    const float* __restrict__ setw, const float* __restrict__ posw,
    const float* __restrict__ lng, const float* __restrict__ lnb,
    const float* __restrict__ loc, const unsigned short* __restrict__ OWt,
    const float* __restrict__ outb, const float* __restrict__ x,
    float* __restrict__ out)
{
    const int SUBS = CLEN / 16;
    const int bx = blockIdx.x;                 // B*CCH*SUBS = 128
    const int b = bx / (CCH * SUBS);
    const int rem = bx % (CCH * SUBS);
    const int c = rem / SUBS;
    const int sub = rem % SUBS;
    const int d = threadIdx.x;
    __shared__ float red[16];
    __shared__ unsigned short ynS[16 * 520];   // [row][d], stride 520

    float s0 = setw[0], s1 = setw[1], s2 = setw[2], s3 = setw[3];
    float mx = fmaxf(fmaxf(s0, s1), fmaxf(s2, s3));
    float e0 = expf(s0 - mx), e1 = expf(s1 - mx), e2 = expf(s2 - mx), e3 = expf(s3 - mx);
    float esum = e0 + e1 + e2 + e3;
    float w4[4] = {e0 / esum, e1 / esum, e2 / esum, e3 / esum};
    float sw = 1.0f / (1.0f + expf(-posw[0]));

    float Pf[72];
    const size_t tb = ((size_t)(b * CCH + c) * 72) * D_ + d;
    #pragma unroll
    for (int ch = 0; ch < 72; ++ch) Pf[ch] = T[tb + (size_t)ch * D_];
    const float lg = lng[d], lb = lnb[d];
    const int lane = d & 63, wv = d >> 6;
    const int l0 = c * CLEN + sub * 16;

    for (int i = 0; i < 16; ++i) {
        const int l = l0 + i;
        const size_t row = (size_t)(b * L_ + l);
        const float4* sc4 = (const float4*)(scal + row * 128);
        float4 gw = sc4[28];
        float gate = gw.x;
        float pb = 0.f, cross = 0.f, pos = 0.f;
        #pragma unroll
        for (int g4 = 0; g4 < 4; ++g4) {
            float qr[4], qi[4];
            *(float4*)qr = sc4[8 + g4]; *(float4*)qi = sc4[12 + g4];
            #pragma unroll
            for (int j = 0; j < 4; ++j) {
                int t = 4 * g4 + j;
                pb += w4[g4] * (Pf[2*t] * qr[j] + Pf[2*t+1] * qi[j]);
            }
        }
        {
            float jqr[4], jqi[4];
            *(float4*)jqr = sc4[18]; *(float4*)jqi = sc4[19];
            #pragma unroll
            for (int pp = 0; pp < 4; ++pp)
                cross += Pf[32+2*pp] * jqr[pp] + Pf[33+2*pp] * jqi[pp];
        }
        #pragma unroll
        for (int g4 = 0; g4 < 4; ++g4) {
            float phr[4], phi[4];
            *(float4*)phr = sc4[20 + g4]; *(float4*)phi = sc4[24 + g4];
            #pragma unroll
            for (int j = 0; j < 4; ++j) {
                int p = 4 * g4 + j;
                pos += Pf[40+2*p] * phr[j] + Pf[41+2*p] * phi[j];
            }
        }
        float addl = gate * ((pb + cross) * 0.2f) + (1.0f - gate) * (sw * pos);
        float y = (loc[row * D_ + d] + addl) / sqrtf(4.0f * (float)(l + 1));
        float s = y, s2v = y * y;
        #pragma unroll
        for (int off = 32; off > 0; off >>= 1) {
            s   += __shfl_down(s, off, 64);
            s2v += __shfl_down(s2v, off, 64);
        }
        if (lane == 0) { red[wv] = s; red[8 + wv] = s2v; }
        __syncthreads();
        float su = 0.f, sq = 0.f;
        #pragma unroll
        for (int w2 = 0; w2 < 8; ++w2) { su += red[w2]; sq += red[8 + w2]; }
        float mu = su * (1.0f / 512.0f);
        float var = sq * (1.0f / 512.0f) - mu * mu;
        float rstd = rsqrtf(var + 1e-5f);
        float yn = (y - mu) * rstd * lg + lb;
        __syncthreads();
        ynS[i * 520 + d] = f2bf(yn);
    }
    __syncthreads();

    // output GEMM: M=16 rows, this wave owns n-cols [w*64, w*64+64)
    const int w = d >> 6;
    const int quad = lane >> 4, r16 = lane & 15;
    const int n0w = w * 64;
    const size_t row0 = (size_t)(b * L_ + l0);

    f32x4 acc[4];
    #pragma unroll
    for (int nt = 0; nt < 4; ++nt) acc[nt] = (f32x4){0.f, 0.f, 0.f, 0.f};

    for (int k0 = 0; k0 < 512; k0 += 32) {
        bf16x8 af = *(const bf16x8*)&ynS[r16 * 520 + k0 + quad * 8];
        #pragma unroll
        for (int nt = 0; nt < 4; ++nt) {
            bf16x8 bfr = *(const bf16x8*)&OWt[(size_t)(n0w + nt * 16 + r16) * 512 + k0 + quad * 8];
            acc[nt] = __builtin_amdgcn_mfma_f32_16x16x32_bf16(af, bfr, acc[nt], 0, 0, 0);
        }
    }
    #pragma unroll
    for (int nt = 0; nt < 4; ++nt) {
        const int n = n0w + nt * 16 + r16;
        const float bn = outb[n];
        #pragma unroll
        for (int i = 0; i < 4; ++i) {
            const size_t m = row0 + quad * 4 + i;
            out[m * 512 + n] = acc[nt][i] + bn + x[m * 512 + n];
        }
    }
}

template<int CCH, int CLEN>
static void run_pipeline(const float* x, const float* keyw, const float* qryw,
                         const float* vw, const float* vb, const float* lng,
                         const float* lnb, const float* outw, const float* outb,
                         const float* setw, const float* pf, const float* posw,
                         const float* g1w, const float* g1b, const float* g2w,
                         const float* g2b, const float* sscale, const float* sbias,
                         const float* rscale, const float* rthr,
                         float* ws, float* out, hipStream_t stream)
{
    float* R    = ws;                              // 2048*896
    float* scal = R + (size_t)NROW * RS;           // 2048*128
    float* loc  = scal + (size_t)NROW * 128;       // 2048*512
    float* T    = loc + (size_t)NROW * D_;         // 2*CCH*72*512
    unsigned short* W = (unsigned short*)(T + (size_t)B_ * CCH * 72 * D_);  // 1408*512

    k_prep_w<<<176, 256, 0, stream>>>(keyw, qryw, g1w, vw, outw, W);
    k_gemm1<<<dim3(7, 32), 256, 0, stream>>>(x, W, g1b, vb, R);
    k_phasor<<<NROW / 4, 256, 0, stream>>>(R, pf, g2w, g2b, scal);
    k_wg<<<B_, 1024, 0, stream>>>(scal, rscale, rthr, sscale, sbias);
    k_passA<CCH, CLEN><<<B_ * CCH * 2, 256, 0, stream>>>(scal, R, setw, posw, loc, T);
    k_scan<CCH><<<288, 256, 0, stream>>>(T);
    k_passB_out<CCH, CLEN><<<B_ * CCH * (CLEN / 16), 512, 0, stream>>>(
        scal, T, setw, posw, lng, lnb, loc, W + (size_t)896 * 512, outb, x, out);
}

extern "C" void kernel_launch(void* const* d_in, const int* in_sizes, int n_in,
                              void* d_out, int out_size, void* d_ws, size_t ws_size,
                              hipStream_t stream)
{
    const float* x      = (const float*)d_in[0];
    const float* keyw   = (const float*)d_in[1];
    const float* qryw   = (const float*)d_in[2];
    const float* vw     = (const float*)d_in[4];
    const float* vb     = (const float*)d_in[5];
    const float* lng    = (const float*)d_in[6];
    const float* lnb    = (const float*)d_in[7];
    const float* outw   = (const float*)d_in[8];
    const float* outb   = (const float*)d_in[9];
    const float* setw   = (const float*)d_in[10];
    const float* pf     = (const float*)d_in[11];
    const float* posw   = (const float*)d_in[12];
    const float* g1w    = (const float*)d_in[13];
    const float* g1b    = (const float*)d_in[14];
    const float* g2w    = (const float*)d_in[15];
    const float* g2b    = (const float*)d_in[16];
    const float* sscale = (const float*)d_in[19];
    const float* sbias  = (const float*)d_in[20];
    const float* rscale = (const float*)d_in[21];
    const float* rthr   = (const float*)d_in[22];

    float* ws  = (float*)d_ws;
    float* out = (float*)d_out;

    const size_t base_bytes = (size_t)(NROW * RS + NROW * 128 + NROW * D_) * 4
                            + (size_t)1408 * 512 * 2;
    const size_t per_cch = (size_t)B_ * 72 * D_ * 4;

    if (ws_size >= base_bytes + 64 * per_cch)
        run_pipeline<64, 16>(x, keyw, qryw, vw, vb, lng, lnb, outw, outb, setw, pf,
                             posw, g1w, g1b, g2w, g2b, sscale, sbias, rscale, rthr,
                             ws, out, stream);
    else
        run_pipeline<32, 32>(x, keyw, qryw, vw, vb, lng, lnb, outw, outb, setw, pf,
                             posw, g1w, g1b, g2w, g2b, sscale, sbias, rscale, rthr,
                             ws, out, stream);
}

// Round 5
// 186.750 us; speedup vs baseline: 1.1033x; 1.1033x over previous
//
#include <hip/hip_runtime.h>
#include <math.h>

#define B_ 2
#define L_ 1024
#define D_ 512
#define NROW (B_*L_)            // 2048
#define RS 896                  // R stride: key16|query16|g1 256|v 512|pad 96
#define PI_F 3.14159274f
#define TWO_PI_F 6.28318548f

typedef __attribute__((ext_vector_type(8))) short bf16x8;
typedef __attribute__((ext_vector_type(4))) float f32x4;

__device__ __forceinline__ unsigned short f2bf(float f) {
    unsigned u = __float_as_uint(f);
    unsigned r = (u + 0x7FFFu + ((u >> 16) & 1u)) >> 16;
    return (unsigned short)r;
}

// ---------------- weight prep: tiled transpose + bf16 cast ----------------
// W[1408][512] bf16, n-major: rows 0-15 key, 16-31 query, 32-287 g1,
// 288-799 v, 800-895 zero, 896-1407 out_w^T
__global__ __launch_bounds__(256) void k_prep_w(
    const float* __restrict__ keyw, const float* __restrict__ qryw,
    const float* __restrict__ g1w, const float* __restrict__ vw,
    const float* __restrict__ outw, unsigned short* __restrict__ W)
{
    const int nt = blockIdx.x % 22;
    const int kt = blockIdx.x / 22;     // 0..7
    const int n0 = nt * 64, k0 = kt * 64;
    __shared__ unsigned short tile[64 * 68];   // [k][n], stride 68
    const int tn = threadIdx.x & 63;
    const int tk4 = threadIdx.x >> 6;   // 0..3
    const int n = n0 + tn;
    const float* src = nullptr; int stride = 0, col = 0;
    if (n < 16)        { src = keyw; stride = 16;  col = n; }
    else if (n < 32)   { src = qryw; stride = 16;  col = n - 16; }
    else if (n < 288)  { src = g1w;  stride = 256; col = n - 32; }
    else if (n < 800)  { src = vw;   stride = 512; col = n - 288; }
    else if (n < 896)  { src = nullptr; }
    else               { src = outw; stride = 512; col = n - 896; }
    #pragma unroll
    for (int r = 0; r < 16; ++r) {
        int k = k0 + tk4 * 16 + r;
        float v = src ? src[(size_t)k * stride + col] : 0.f;
        tile[(tk4 * 16 + r) * 68 + tn] = f2bf(v);
    }
    __syncthreads();
    #pragma unroll
    for (int r = 0; r < 16; ++r) {
        int nn = n0 + tk4 * 16 + r;
        W[(size_t)nn * 512 + k0 + tn] = tile[tn * 68 + tk4 * 16 + r];
    }
}

// ---------------- GEMM1 (MFMA): R[2048][896] = x @ W[0:896]^T, fp32-A inline cast ----------------
__global__ __launch_bounds__(256) void k_gemm1(
    const float* __restrict__ x,             // [2048][512] fp32
    const unsigned short* __restrict__ Bt,   // [896][512] bf16 (n-major)
    const float* __restrict__ g1b, const float* __restrict__ vb,
    float* __restrict__ C)
{
    __shared__ unsigned short As[64 * 32];
    __shared__ unsigned short Bs[128 * 32];
    const int tid = threadIdx.x;
    const int w = tid >> 6;
    const int lane = tid & 63;
    const int m0 = blockIdx.y * 64;
    const int n0 = blockIdx.x * 128;
    const int srow = tid >> 2;          // 0..63
    const int scol = (tid & 3) * 8;     // 0,8,16,24

    f32x4 acc[4][2];
    #pragma unroll
    for (int mt = 0; mt < 4; ++mt)
        #pragma unroll
        for (int nt = 0; nt < 2; ++nt)
            acc[mt][nt] = (f32x4){0.f, 0.f, 0.f, 0.f};

    const float* ap = x + (size_t)(m0 + srow) * 512 + scol;
    const unsigned short* bp0 = Bt + (size_t)(n0 + srow) * 512 + scol;
    const unsigned short* bp1 = Bt + (size_t)(n0 + 64 + srow) * 512 + scol;
    const int quad = lane >> 4, r16 = lane & 15;

    for (int k0 = 0; k0 < 512; k0 += 32) {
        float4 a0 = *(const float4*)(ap + k0);
        float4 a1 = *(const float4*)(ap + k0 + 4);
        int4 bv0 = *(const int4*)(bp0 + k0);
        int4 bv1 = *(const int4*)(bp1 + k0);
        int4 av;
        av.x = (int)f2bf(a0.x) | ((int)f2bf(a0.y) << 16);
        av.y = (int)f2bf(a0.z) | ((int)f2bf(a0.w) << 16);
        av.z = (int)f2bf(a1.x) | ((int)f2bf(a1.y) << 16);
        av.w = (int)f2bf(a1.z) | ((int)f2bf(a1.w) << 16);
        __syncthreads();
        *(int4*)&As[srow * 32 + scol] = av;
        *(int4*)&Bs[srow * 32 + scol] = bv0;
        *(int4*)&Bs[(64 + srow) * 32 + scol] = bv1;
        __syncthreads();
        bf16x8 af[4], bfr[2];
        #pragma unroll
        for (int mt = 0; mt < 4; ++mt)
            af[mt] = *(const bf16x8*)&As[(mt * 16 + r16) * 32 + quad * 8];
        #pragma unroll
        for (int nt = 0; nt < 2; ++nt)
            bfr[nt] = *(const bf16x8*)&Bs[(w * 32 + nt * 16 + r16) * 32 + quad * 8];
        #pragma unroll
        for (int mt = 0; mt < 4; ++mt)
            #pragma unroll
            for (int nt = 0; nt < 2; ++nt)
                acc[mt][nt] = __builtin_amdgcn_mfma_f32_16x16x32_bf16(
                    af[mt], bfr[nt], acc[mt][nt], 0, 0, 0);
    }

    #pragma unroll
    for (int mt = 0; mt < 4; ++mt) {
        #pragma unroll
        for (int nt = 0; nt < 2; ++nt) {
            const int n = n0 + w * 32 + nt * 16 + r16;
            float bias = 0.f;
            if (n >= 288 && n < 800) bias = vb[n - 288];
            else if (n >= 32 && n < 288) bias = g1b[n - 32];
            #pragma unroll
            for (int i = 0; i < 4; ++i) {
                const int m = m0 + mt * 16 + quad * 4 + i;
                C[(size_t)m * RS + n] = acc[mt][nt][i] + bias;
            }
        }
    }
}

// ---------------- phasors, jk/jq, pos phasors, gate (4 rows/block, wave=row) ----------------
__global__ __launch_bounds__(256) void k_phasor(
    const float* __restrict__ R, const float* __restrict__ pf,
    const float* __restrict__ g2w, const float* __restrict__ g2b,
    float* __restrict__ scal)
{
    const int row = blockIdx.x * 4 + (threadIdx.x >> 6);
    const int lane = threadIdx.x & 63;
    const int l = row & (L_ - 1);
    float* sc = scal + (size_t)row * 128;
    const float* r = R + (size_t)row * RS;

    float part = 0.f;
    #pragma unroll
    for (int j = 0; j < 4; ++j) {
        float v = r[32 + lane * 4 + j];
        float h = 0.5f * v * (1.0f + erff(v * 0.70710678f));
        part += h * g2w[lane * 4 + j];
    }
    #pragma unroll
    for (int off = 32; off > 0; off >>= 1) part += __shfl_down(part, off, 64);
    if (lane == 0) sc[112] = 1.0f / (1.0f + expf(-(part + g2b[0])));

    float pr = 1.f, pim = 0.f;
    if (lane < 32) {
        float a = tanhf(r[lane]) * PI_F;
        float sv, cv;
        sincosf(a, &sv, &cv);
        int t = lane & 15;
        if (lane < 16) { sc[t] = cv; sc[16 + t] = sv; }
        else           { sc[32 + t] = cv; sc[48 + t] = sv; }
        pr = cv; pim = sv;
    }
    #pragma unroll
    for (int m = 4; m <= 8; m <<= 1) {
        float orr = __shfl_xor(pr, m, 64);
        float oii = __shfl_xor(pim, m, 64);
        float nr = pr * orr - pim * oii;
        float ni = pr * oii + pim * orr;
        pr = nr; pim = ni;
    }
    if (lane < 4)                     { sc[64 + lane] = pr; sc[68 + lane] = pim; }
    else if (lane >= 16 && lane < 20) { sc[72 + lane - 16] = pr; sc[76 + lane - 16] = pim; }

    if (lane >= 32 && lane < 48) {
        int p = lane - 32;
        float theta = ((float)l * pf[p]) * TWO_PI_F;
        float sv, cv;
        sincosf(theta, &sv, &cv);
        sc[80 + p] = cv;
        sc[96 + p] = sv;
    }
}

// ---------------- wg: block scan of jk over L, surprise gate ----------------
__global__ __launch_bounds__(1024) void k_wg(
    float* __restrict__ scal,
    const float* __restrict__ res_scale, const float* __restrict__ res_thr,
    const float* __restrict__ sur_scale, const float* __restrict__ sur_bias)
{
    const int b = blockIdx.x;
    const int l = threadIdx.x;
    const size_t row = (size_t)(b * L_ + l) * 128;
    float v[8], own[8];
    #pragma unroll
    for (int c2 = 0; c2 < 8; ++c2) { v[c2] = scal[row + 64 + c2]; own[c2] = v[c2]; }
    const int lane = l & 63;
    const int wave = l >> 6;
    #pragma unroll
    for (int off = 1; off < 64; off <<= 1) {
        float o[8];
        #pragma unroll
        for (int c2 = 0; c2 < 8; ++c2) o[c2] = __shfl_up(v[c2], off, 64);
        if (lane >= off) {
            #pragma unroll
            for (int c2 = 0; c2 < 8; ++c2) v[c2] += o[c2];
        }
    }
    __shared__ float wtot[16][8];
    if (lane == 63) {
        #pragma unroll
        for (int c2 = 0; c2 < 8; ++c2) wtot[wave][c2] = v[c2];
    }
    __syncthreads();
    float pre[8] = {0,0,0,0,0,0,0,0};
    for (int w2 = 0; w2 < wave; ++w2) {
        #pragma unroll
        for (int c2 = 0; c2 < 8; ++c2) pre[c2] += wtot[w2][c2];
    }
    float km[8];
    #pragma unroll
    for (int c2 = 0; c2 < 8; ++c2) km[c2] = pre[c2] + v[c2] - own[c2];
    float mag = 0.f;
    #pragma unroll
    for (int pp = 0; pp < 4; ++pp) {
        float jqr = scal[row + 72 + pp], jqi = scal[row + 76 + pp];
        float re = km[pp] * jqr + km[4 + pp] * jqi;
        float im = km[4 + pp] * jqr - km[pp] * jqi;
        mag += sqrtf(re * re + im * im);
    }
    mag *= 0.25f;
    float posn = fmaxf((float)l, 1.0f);
    float nres = mag / sqrtf(posn);
    float scl = fminf(fmaxf(res_scale[0], 1.0f), 20.0f);
    float thr = fminf(fmaxf(res_thr[0], 0.1f), 0.9f);
    float sur = 0.5f * (1.0f - tanhf(scl * (nres - thr)));
    float wgv = 1.0f / (1.0f + expf(-(sur_scale[0] * (sur - 0.5f) + sur_bias[0])));
    scal[row + 113] = wgv;
}

// ---------------- pass A: chunked scans, local contributions + chunk totals ----------------
template<int CCH, int CLEN>
__global__ __launch_bounds__(256) void k_passA(
    const float* __restrict__ scal, const float* __restrict__ R,
    const float* __restrict__ setw, const float* __restrict__ posw,
    float* __restrict__ loc, float* __restrict__ T)
{
    const int bx = blockIdx.x;           // B*CCH*2
    const int b = bx / (CCH * 2);
    const int rem = bx % (CCH * 2);
    const int c = rem >> 1;
    const int half = rem & 1;
    const int d = half * 256 + threadIdx.x;

    float s0 = setw[0], s1 = setw[1], s2 = setw[2], s3 = setw[3];
    float mx = fmaxf(fmaxf(s0, s1), fmaxf(s2, s3));
    float e0 = expf(s0 - mx), e1 = expf(s1 - mx), e2 = expf(s2 - mx), e3 = expf(s3 - mx);
    float esum = e0 + e1 + e2 + e3;
    float w[4] = {e0 / esum, e1 / esum, e2 / esum, e3 / esum};
    float sw = 1.0f / (1.0f + expf(-posw[0]));

    float Sr[16] = {}, Si[16] = {}, Xr[4] = {}, Xi[4] = {}, Pr[16] = {}, Pi[16] = {};

    for (int i = 0; i < CLEN; ++i) {
        const int l = c * CLEN + i;
        const size_t row = (size_t)(b * L_ + l);
        const float4* sc4 = (const float4*)(scal + row * 128);
        float V = R[row * RS + 288 + d];
        float4 gw = sc4[28];
        float gate = gw.x, wg = gw.y;
        float Vg = V * wg;
        float pb = 0.f, cross = 0.f, pos = 0.f;
        #pragma unroll
        for (int g4 = 0; g4 < 4; ++g4) {
            float kr[4], ki[4], qr[4], qi[4];
            *(float4*)kr = sc4[g4];      *(float4*)ki = sc4[4 + g4];
            *(float4*)qr = sc4[8 + g4];  *(float4*)qi = sc4[12 + g4];
            #pragma unroll
            for (int j = 0; j < 4; ++j) {
                int t = 4 * g4 + j;
                Sr[t] += kr[j] * Vg; Si[t] += ki[j] * Vg;
                pb += w[g4] * (Sr[t] * qr[j] + Si[t] * qi[j]);
            }
        }
        {
            float jkr[4], jki[4], jqr[4], jqi[4];
            *(float4*)jkr = sc4[16]; *(float4*)jki = sc4[17];
            *(float4*)jqr = sc4[18]; *(float4*)jqi = sc4[19];
            #pragma unroll
            for (int pp = 0; pp < 4; ++pp) {
                Xr[pp] += jkr[pp] * Vg; Xi[pp] += jki[pp] * Vg;
                cross += Xr[pp] * jqr[pp] + Xi[pp] * jqi[pp];
            }
        }
        #pragma unroll
        for (int g4 = 0; g4 < 4; ++g4) {
            float phr[4], phi[4];
            *(float4*)phr = sc4[20 + g4]; *(float4*)phi = sc4[24 + g4];
            #pragma unroll
            for (int j = 0; j < 4; ++j) {
                int p = 4 * g4 + j;
                Pr[p] += phr[j] * V; Pi[p] += phi[j] * V;
                pos += Pr[p] * phr[j] + Pi[p] * phi[j];
            }
        }
        float comb = gate * ((pb + cross) * 0.2f) + (1.0f - gate) * (sw * pos);
        loc[row * D_ + d] = comb;
    }
    const size_t tb = ((size_t)(b * CCH + c) * 72) * D_ + d;
    #pragma unroll
    for (int t = 0; t < 16; ++t) { T[tb + (size_t)(2*t)*D_] = Sr[t]; T[tb + (size_t)(2*t+1)*D_] = Si[t]; }
    #pragma unroll
    for (int pp = 0; pp < 4; ++pp) { T[tb + (size_t)(32+2*pp)*D_] = Xr[pp]; T[tb + (size_t)(33+2*pp)*D_] = Xi[pp]; }
    #pragma unroll
    for (int p = 0; p < 16; ++p) { T[tb + (size_t)(40+2*p)*D_] = Pr[p]; T[tb + (size_t)(41+2*p)*D_] = Pi[p]; }
}

// ---------------- in-place exclusive scan over chunk totals (8-wide ILP batches) ----------------
template<int CCH>
__global__ __launch_bounds__(256) void k_scan(float* __restrict__ T)
{
    const int idx = blockIdx.x * 256 + threadIdx.x;     // < 2*72*512 = 73728
    const int d = idx & 511;
    const int ch = (idx >> 9) % 72;
    const int b = idx / (512 * 72);
    const size_t base = ((size_t)b * CCH * 72 + ch) * D_ + d;
    const size_t cstride = (size_t)72 * D_;
    float run = 0.f;
    for (int c0 = 0; c0 < CCH; c0 += 8) {
        float v[8];
        #pragma unroll
        for (int j = 0; j < 8; ++j) v[j] = T[base + (size_t)(c0 + j) * cstride];
        #pragma unroll
        for (int j = 0; j < 8; ++j) {
            T[base + (size_t)(c0 + j) * cstride] = run;
            run += v[j];
        }
    }
}

// ---------------- pass B: add prefix, combine, /norm, LayerNorm, bf16 out (8 rows/block) ----------------
template<int CCH, int CLEN>
__global__ __launch_bounds__(512) void k_passB(
    const float* __restrict__ scal, const float* __restrict__ T,
    const float* __restrict__ setw, const float* __restrict__ posw,
    const float* __restrict__ lng, const float* __restrict__ lnb,
    const float* __restrict__ loc, unsigned short* __restrict__ locb)
{
    const int SUBS = CLEN / 8;
    const int bx = blockIdx.x;                 // B*CCH*SUBS
    const int b = bx / (CCH * SUBS);
    const int rem = bx % (CCH * SUBS);
    const int c = rem / SUBS;
    const int sub = rem % SUBS;
    const int d = threadIdx.x;
    __shared__ float red[16];

    float s0 = setw[0], s1 = setw[1], s2 = setw[2], s3 = setw[3];
    float mx = fmaxf(fmaxf(s0, s1), fmaxf(s2, s3));
    float e0 = expf(s0 - mx), e1 = expf(s1 - mx), e2 = expf(s2 - mx), e3 = expf(s3 - mx);
    float esum = e0 + e1 + e2 + e3;
    float w[4] = {e0 / esum, e1 / esum, e2 / esum, e3 / esum};
    float sw = 1.0f / (1.0f + expf(-posw[0]));

    float Pf[72];
    const size_t tb = ((size_t)(b * CCH + c) * 72) * D_ + d;
    #pragma unroll
    for (int ch = 0; ch < 72; ++ch) Pf[ch] = T[tb + (size_t)ch * D_];
    const float lg = lng[d], lb = lnb[d];
    const int lane = d & 63, wv = d >> 6;

    for (int i = 0; i < 8; ++i) {
        const int l = c * CLEN + sub * 8 + i;
        const size_t row = (size_t)(b * L_ + l);
        const float4* sc4 = (const float4*)(scal + row * 128);
        float4 gw = sc4[28];
        float gate = gw.x;
        float pb = 0.f, cross = 0.f, pos = 0.f;
        #pragma unroll
        for (int g4 = 0; g4 < 4; ++g4) {
            float qr[4], qi[4];
            *(float4*)qr = sc4[8 + g4]; *(float4*)qi = sc4[12 + g4];
            #pragma unroll
            for (int j = 0; j < 4; ++j) {
                int t = 4 * g4 + j;
                pb += w[g4] * (Pf[2*t] * qr[j] + Pf[2*t+1] * qi[j]);
            }
        }
        {
            float jqr[4], jqi[4];
            *(float4*)jqr = sc4[18]; *(float4*)jqi = sc4[19];
            #pragma unroll
            for (int pp = 0; pp < 4; ++pp)
                cross += Pf[32+2*pp] * jqr[pp] + Pf[33+2*pp] * jqi[pp];
        }
        #pragma unroll
        for (int g4 = 0; g4 < 4; ++g4) {
            float phr[4], phi[4];
            *(float4*)phr = sc4[20 + g4]; *(float4*)phi = sc4[24 + g4];
            #pragma unroll
            for (int j = 0; j < 4; ++j) {
                int p = 4 * g4 + j;
                pos += Pf[40+2*p] * phr[j] + Pf[41+2*p] * phi[j];
            }
        }
        float addl = gate * ((pb + cross) * 0.2f) + (1.0f - gate) * (sw * pos);
        float y = (loc[row * D_ + d] + addl) / sqrtf(4.0f * (float)(l + 1));
        float s = y, s2v = y * y;
        #pragma unroll
        for (int off = 32; off > 0; off >>= 1) {
            s   += __shfl_down(s, off, 64);
            s2v += __shfl_down(s2v, off, 64);
        }
        if (lane == 0) { red[wv] = s; red[8 + wv] = s2v; }
        __syncthreads();
        float su = 0.f, sq = 0.f;
        #pragma unroll
        for (int w2 = 0; w2 < 8; ++w2) { su += red[w2]; sq += red[8 + w2]; }
        float mu = su * (1.0f / 512.0f);
        float var = sq * (1.0f / 512.0f) - mu * mu;
        float rstd = rsqrtf(var + 1e-5f);
        float yn = (y - mu) * rstd * lg + lb;
        __syncthreads();
        locb[row * D_ + d] = f2bf(yn);
    }
}

// ---------------- out GEMM (MFMA, 64x64 tiles): out = x + yn @ out_w + out_b ----------------
__global__ __launch_bounds__(256) void k_gemm_out(
    const unsigned short* __restrict__ A,    // locb [2048][512] bf16
    const unsigned short* __restrict__ Bt,   // OWt [512][512] bf16 (n-major)
    const float* __restrict__ bias, const float* __restrict__ resid,
    float* __restrict__ out)
{
    __shared__ unsigned short As[64 * 32];
    __shared__ unsigned short Bs[64 * 32];
    const int tid = threadIdx.x;
    const int w = tid >> 6;
    const int lane = tid & 63;
    const int m0 = blockIdx.y * 64;
    const int n0 = blockIdx.x * 64;
    const int srow = tid >> 2;
    const int scol = (tid & 3) * 8;
    const int quad = lane >> 4, r16 = lane & 15;

    f32x4 acc[4];
    #pragma unroll
    for (int mt = 0; mt < 4; ++mt) acc[mt] = (f32x4){0.f, 0.f, 0.f, 0.f};

    const unsigned short* ap = A  + (size_t)(m0 + srow) * 512 + scol;
    const unsigned short* bp = Bt + (size_t)(n0 + srow) * 512 + scol;

    for (int k0 = 0; k0 < 512; k0 += 32) {
        int4 av = *(const int4*)(ap + k0);
        int4 bv = *(const int4*)(bp + k0);
        __syncthreads();
        *(int4*)&As[srow * 32 + scol] = av;
        *(int4*)&Bs[srow * 32 + scol] = bv;
        __syncthreads();
        bf16x8 bfr = *(const bf16x8*)&Bs[(w * 16 + r16) * 32 + quad * 8];
        #pragma unroll
        for (int mt = 0; mt < 4; ++mt) {
            bf16x8 af = *(const bf16x8*)&As[(mt * 16 + r16) * 32 + quad * 8];
            acc[mt] = __builtin_amdgcn_mfma_f32_16x16x32_bf16(af, bfr, acc[mt], 0, 0, 0);
        }
    }
    const int n = n0 + w * 16 + r16;
    const float bn = bias[n];
    #pragma unroll
    for (int mt = 0; mt < 4; ++mt) {
        #pragma unroll
        for (int i = 0; i < 4; ++i) {
            const int m = m0 + mt * 16 + quad * 4 + i;
            out[(size_t)m * 512 + n] = acc[mt][i] + bn + resid[(size_t)m * 512 + n];
        }
    }
}

template<int CCH, int CLEN>
static void run_pipeline(const float* x, const float* keyw, const float* qryw,
                         const float* vw, const float* vb, const float* lng,
                         const float* lnb, const float* outw, const float* outb,
                         const float* setw, const float* pf, const float* posw,
                         const float* g1w, const float* g1b, const float* g2w,
                         const float* g2b, const float* sscale, const float* sbias,
                         const float* rscale, const float* rthr,
                         float* ws, float* out, hipStream_t stream)
{
    float* R    = ws;                              // 2048*896
    float* scal = R + (size_t)NROW * RS;           // 2048*128
    float* loc  = scal + (size_t)NROW * 128;       // 2048*512
    float* T    = loc + (size_t)NROW * D_;         // 2*CCH*72*512
    unsigned short* W    = (unsigned short*)(T + (size_t)B_ * CCH * 72 * D_);  // 1408*512
    unsigned short* locb = W + (size_t)1408 * 512;                             // 2048*512

    k_prep_w<<<176, 256, 0, stream>>>(keyw, qryw, g1w, vw, outw, W);
    k_gemm1<<<dim3(7, 32), 256, 0, stream>>>(x, W, g1b, vb, R);
    k_phasor<<<NROW / 4, 256, 0, stream>>>(R, pf, g2w, g2b, scal);
    k_wg<<<B_, 1024, 0, stream>>>(scal, rscale, rthr, sscale, sbias);
    k_passA<CCH, CLEN><<<B_ * CCH * 2, 256, 0, stream>>>(scal, R, setw, posw, loc, T);
    k_scan<CCH><<<288, 256, 0, stream>>>(T);
    k_passB<CCH, CLEN><<<B_ * CCH * (CLEN / 8), 512, 0, stream>>>(
        scal, T, setw, posw, lng, lnb, loc, locb);
    k_gemm_out<<<dim3(8, 32), 256, 0, stream>>>(
        locb, W + (size_t)896 * 512, outb, x, out);
}

extern "C" void kernel_launch(void* const* d_in, const int* in_sizes, int n_in,
                              void* d_out, int out_size, void* d_ws, size_t ws_size,
                              hipStream_t stream)
{
    const float* x      = (const float*)d_in[0];
    const float* keyw   = (const float*)d_in[1];
    const float* qryw   = (const float*)d_in[2];
    const float* vw     = (const float*)d_in[4];
    const float* vb     = (const float*)d_in[5];
    const float* lng    = (const float*)d_in[6];
    const float* lnb    = (const float*)d_in[7];
    const float* outw   = (const float*)d_in[8];
    const float* outb   = (const float*)d_in[9];
    const float* setw   = (const float*)d_in[10];
    const float* pf     = (const float*)d_in[11];
    const float* posw   = (const float*)d_in[12];
    const float* g1w    = (const float*)d_in[13];
    const float* g1b    = (const float*)d_in[14];
    const float* g2w    = (const float*)d_in[15];
    const float* g2b    = (const float*)d_in[16];
    const float* sscale = (const float*)d_in[19];
    const float* sbias  = (const float*)d_in[20];
    const float* rscale = (const float*)d_in[21];
    const float* rthr   = (const float*)d_in[22];

    float* ws  = (float*)d_ws;
    float* out = (float*)d_out;

    const size_t base_bytes = (size_t)(NROW * RS + NROW * 128 + NROW * D_) * 4
                            + ((size_t)1408 * 512 + (size_t)NROW * 512) * 2;
    const size_t per_cch = (size_t)B_ * 72 * D_ * 4;

    if (ws_size >= base_bytes + 64 * per_cch)
        run_pipeline<64, 16>(x, keyw, qryw, vw, vb, lng, lnb, outw, outb, setw, pf,
                             posw, g1w, g1b, g2w, g2b, sscale, sbias, rscale, rthr,
                             ws, out, stream);
    else
        run_pipeline<32, 32>(x, keyw, qryw, vw, vb, lng, lnb, outw, outb, setw, pf,
                             posw, g1w, g1b, g2w, g2b, sscale, sbias, rscale, rthr,
                             ws, out, stream);
}